// Round 1
// baseline (5713.417 us; speedup 1.0000x reference)
//
#include <hip/hip_runtime.h>
#include <hip/hip_bf16.h>

typedef _Float16 f16x8 __attribute__((ext_vector_type(8)));
typedef float f32x4 __attribute__((ext_vector_type(4)));

#define BATCH 256
#define UD 128
#define K1 512
#define LDA 520    // 512 + 8 f16 pad
#define LDA2 392   // 384 + 8 f16 pad
#define CELLSZ (BATCH*UD)          // floats per grid cell

// Workspace layout (ws is 512 MiB — harness poison fill shows 536,870,912 B):
//   WT    @ 0           : 896*512*2        =    917,504 B
//   B2T   @ 917,504     : 128*512*2        =    131,072 B
//   X     @ 1,048,576   : 1024*256*128*2   = 67,108,864 B
//   H     @ 68,157,440  : 1024*256*128*4   = 134,217,728 B  (write-once per cell, no ring)
//   flags @ 202,375,168 : 1024*8*4         =     32,768 B
#define WS_B2T  917504
#define WS_X    1048576
#define WS_H    68157440ull
#define WS_FLAG 202375168ull

// inputs (B,C,32,32) fp32 -> X[(i*32+j)][b][c] f16  (LDS transpose, coalesced both sides)
__global__ void k_reorder(const float* __restrict__ in, _Float16* __restrict__ X){
  int b = blockIdx.x, i = blockIdx.y;
  __shared__ float tile[128][33];
  int tid = threadIdx.x;
#pragma unroll
  for (int r=0;r<16;++r){
    int c = r*8 + (tid>>5), j = tid&31;
    tile[c][j] = in[(((size_t)b*128 + c)*32 + i)*32 + j];
  }
  __syncthreads();
#pragma unroll
  for (int r=0;r<16;++r){
    int j = r*2 + (tid>>7), c = tid&127;
    X[((size_t)(i*32 + j)*256 + b)*128 + c] = (_Float16)tile[c][j];
  }
}

// WT[n][k] = W[k][n]; B2T[n][k] = (k<384 ? Umat[k][n] : w_ij[k-384][n]); zero dep flags.
__global__ void k_prep(const float* __restrict__ W,
                       const float* __restrict__ Um,
                       const float* __restrict__ wij,
                       _Float16* __restrict__ WT, _Float16* __restrict__ B2T,
                       unsigned* __restrict__ flags){
  int idx = blockIdx.x*256 + threadIdx.x;
  if (idx < 896*512){
    int n = idx >> 9, k = idx & 511;
    WT[idx] = (_Float16)W[k*896 + n];
  }
  if (idx < 128*512){
    int n = idx >> 9, k = idx & 511;
    float v = (k < 384) ? Um[k*128 + n] : wij[(k-384)*128 + n];
    B2T[idx] = (_Float16)v;
  }
  if (idx < 1024*8) flags[idx] = 0;   // ws is poisoned each run -> must zero
}

// final h lives at cell (31,31) = 1023
__global__ void k_out(const float* __restrict__ H, float* __restrict__ out){
  int t = blockIdx.x*256 + threadIdx.x;
  out[t] = H[(size_t)1023*CELLSZ + t];
}

// GEMM1 pass over 7 of the 14 n-tiles (two-pass split keeps live VGPRs < 256 so
// __launch_bounds__(256,2) compiles spill-free; r-tiles die between passes).
// Tile map: tt 0..5 -> r cols wave*96 + tt*16 ; tt 6..13 -> z gate g=(tt-6)>>1, sub=(tt-6)&1.
template<int T0>
__device__ __forceinline__ void gemm1_pass(const _Float16* Al,
    const _Float16* __restrict__ WT, int wave, int l15, int quad,
    f32x4 (&acc)[2][7])
{
  const _Float16* bptr[7];
#pragma unroll
  for (int t=0;t<7;++t){
    const int tt = T0 + t;
    const int n = (tt<6) ? (wave*96 + tt*16)
                         : (384 + ((tt-6)>>1)*128 + wave*32 + ((tt-6)&1)*16);
    bptr[t] = WT + (size_t)(n + l15)*K1 + quad*8;
  }
  f16x8 bcur[7], bnxt[7];
#pragma unroll
  for (int t=0;t<7;++t) bcur[t] = *(const f16x8*)(bptr[t]);
#pragma unroll
  for (int ks=0; ks<16; ++ks){
    const int kb = ks*32 + quad*8;
    if (ks < 15){
#pragma unroll
      for (int t=0;t<7;++t) bnxt[t] = *(const f16x8*)(bptr[t] + (ks+1)*32);
    }
    f16x8 a0 = *(const f16x8*)&Al[l15*LDA + kb];
    f16x8 a1 = *(const f16x8*)&Al[(16+l15)*LDA + kb];
#pragma unroll
    for (int t=0;t<7;++t){
      acc[0][t] = __builtin_amdgcn_mfma_f32_16x16x32_f16(a0, bcur[t], acc[0][t], 0,0,0);
      acc[1][t] = __builtin_amdgcn_mfma_f32_16x16x32_f16(a1, bcur[t], acc[1][t], 0,0,0);
    }
#pragma unroll
    for (int t=0;t<7;++t) bcur[t] = bnxt[t];
  }
}

// R5: persistent wavefront kernel. One launch replaces the 63 k_diag launches.
// Block (c, strip) walks track d = c .. 62-c, cell i = max(0,d-31)+c, j = d-i.
// Per-cell per-strip flags (agent-scope atomics) gate only the 3 true neighbor
// deps -> the diagonal wavefront pipelines across blocks instead of barriering.
// h exchange stays fp32 (numerics identical to multi-launch version); H is
// write-once so consumer plain loads are first-touch fresh (no buffer_inv ever,
// WT stays L2-resident for all 63 steps). Producer release-store = wbl2 only.
__global__ __launch_bounds__(256, 2) void k_sweep(
    const _Float16* __restrict__ X,
    float* __restrict__ H,
    const _Float16* __restrict__ WT,
    const _Float16* __restrict__ B2T,
    const float* __restrict__ bias,
    unsigned* __restrict__ flags)
{
  __shared__ __align__(16) _Float16 Al[32*LDA];
  __shared__ __align__(16) _Float16 A2l[32*LDA2];

  const int c     = blockIdx.x;        // track index (32 tracks)
  const int strip = blockIdx.y;        // batch strip (8 x 32 rows)
  const int bs    = strip*32;

  const int tid  = threadIdx.x;
  const int wave = tid >> 6;
  const int lane = tid & 63;
  const int l15  = lane & 15;
  const int quad = lane >> 4;

  for (int d = c; d <= 62 - c; ++d){
    const int i0 = (d > 31) ? (d - 31) : 0;
    const int i  = i0 + c;
    const int j  = d - i;
    const bool hasT = (i >= 1);
    const bool hasL = (j >= 1);
    const bool hasD = hasT && hasL;

    const int cell = i*32 + j;
    const _Float16* Xc   = X + (size_t)cell*CELLSZ;
    float*       hOut    = H + (size_t)cell*CELLSZ;
    const float* hTop    = H + (size_t)(cell-32)*CELLSZ;  // valid iff hasT
    const float* hLeft   = H + (size_t)(cell-1)*CELLSZ;   // valid iff hasL
    const float* hDiag   = H + (size_t)(cell-33)*CELLSZ;  // valid iff hasD

    // ---- (A) stage s_ij + zero-fill absent h regions (no deps; overlaps the poll)
    for (int v = tid; v < 512; v += 256){
      int m = v >> 4, kc = (v & 15) << 3;
      *(uint4*)&Al[m*LDA + 384 + kc] = *(const uint4*)(Xc + (size_t)(bs+m)*UD + kc);
    }
    if (!hasT || !hasL){
#pragma unroll
      for (int r=0;r<3;++r){
        const bool present = (r==0) ? hasT : ((r==1) ? hasL : hasD);
        if (!present){
          for (int v = tid; v < 1024; v += 256){
            int m = v >> 5, kc = (v & 31) << 2;
            *(ushort4*)&Al[m*LDA + r*128 + kc] = make_ushort4(0,0,0,0);
          }
        }
      }
    }

    // ---- (B) wait for the 3 producer cells (same strip). Lanes 0..2 poll in lockstep.
    if (tid < 3){
      const unsigned* f = nullptr;
      if (tid==0 && hasT) f = &flags[(size_t)(cell-32)*8 + strip];
      if (tid==1 && hasL) f = &flags[(size_t)(cell-1)*8 + strip];
      if (tid==2 && hasD) f = &flags[(size_t)(cell-33)*8 + strip];
      if (f){
        while (__hip_atomic_load(f, __ATOMIC_RELAXED, __HIP_MEMORY_SCOPE_AGENT) == 0)
          __builtin_amdgcn_s_sleep(1);
      }
    }
    __syncthreads();

    // ---- (C) stage present neighbor h (fp32 -> f16), coalesced float4
    {
      const float* srcs[3];
      srcs[0] = hasT ? hTop : nullptr;
      srcs[1] = hasL ? hLeft : nullptr;
      srcs[2] = hasD ? hDiag : nullptr;
#pragma unroll
      for (int r=0;r<3;++r){
        const float* src = srcs[r];
        if (src){
          for (int v = tid; v < 1024; v += 256){
            int m = v >> 5, kc = (v & 31) << 2;
            float4 f4 = *(const float4*)(src + (size_t)(bs+m)*UD + kc);
            union { _Float16 h[4]; ushort4 u; } p;
            p.h[0]=(_Float16)f4.x; p.h[1]=(_Float16)f4.y;
            p.h[2]=(_Float16)f4.z; p.h[3]=(_Float16)f4.w;
            *(ushort4*)&Al[m*LDA + r*128 + kc] = p.u;
          }
        }
      }
    }
    __syncthreads();

    // ---- GEMM1 pass A: tiles 0..6 (all 6 r-tiles + z tile 6)
    f32x4 accA[2][7];
#pragma unroll
    for (int a=0;a<2;++a)
#pragma unroll
      for (int t=0;t<7;++t) accA[a][t] = (f32x4){0.f,0.f,0.f,0.f};
    gemm1_pass<0>(Al, WT, wave, l15, quad, accA);

    // ---- r = hard_sigmoid(.); A2 = r * h (re-ordered) -> LDS. r-tiles die here.
#pragma unroll
    for (int mt=0;mt<2;++mt)
#pragma unroll
      for (int t=0;t<6;++t){
        const int col = wave*96 + t*16 + l15;
        const float br = bias[col];
        const int hcol = (col < 128) ? (128 + col) : ((col < 256) ? (col - 128) : col);
#pragma unroll
        for (int rg=0;rg<4;++rg){
          const int m = mt*16 + quad*4 + rg;
          float r = 0.2f*(accA[mt][t][rg] + br) + 0.5f;
          r = fminf(fmaxf(r, 0.f), 1.f);
          float h = (float)Al[m*LDA + hcol];
          A2l[m*LDA2 + col] = (_Float16)(r*h);
        }
      }

    // ---- GEMM1 pass B: tiles 7..13 (remaining z-tiles)
    f32x4 accB[2][7];
#pragma unroll
    for (int a=0;a<2;++a)
#pragma unroll
      for (int t=0;t<7;++t) accB[a][t] = (f32x4){0.f,0.f,0.f,0.f};
    gemm1_pass<7>(Al, WT, wave, l15, quad, accB);
    __syncthreads();   // A2l writes (all waves) visible before GEMM2 reads

    // ---- GEMM2: (32 x 512) @ (512 x 128); k>=384 (s_ij) read from Al
    f32x4 acc2[2][2];
#pragma unroll
    for (int a=0;a<2;++a){ acc2[a][0]=(f32x4){0.f,0.f,0.f,0.f}; acc2[a][1]=(f32x4){0.f,0.f,0.f,0.f}; }
    {
      const _Float16* b2ptr[2];
#pragma unroll
      for (int s=0;s<2;++s) b2ptr[s] = B2T + (size_t)(wave*32 + s*16 + l15)*K1 + quad*8;
      f16x8 b2cur[2], b2nxt[2];
#pragma unroll
      for (int s=0;s<2;++s) b2cur[s] = *(const f16x8*)(b2ptr[s]);
#pragma unroll
      for (int ks=0; ks<16; ++ks){
        const int kb = ks*32 + quad*8;
        if (ks < 15){
#pragma unroll
          for (int s=0;s<2;++s) b2nxt[s] = *(const f16x8*)(b2ptr[s] + (ks+1)*32);
        }
        f16x8 a0, a1;
        if (ks < 12){
          a0 = *(const f16x8*)&A2l[l15*LDA2 + kb];
          a1 = *(const f16x8*)&A2l[(16+l15)*LDA2 + kb];
        } else {
          a0 = *(const f16x8*)&Al[l15*LDA + kb];
          a1 = *(const f16x8*)&Al[(16+l15)*LDA + kb];
        }
#pragma unroll
        for (int s=0;s<2;++s){
          acc2[0][s] = __builtin_amdgcn_mfma_f32_16x16x32_f16(a0, b2cur[s], acc2[0][s], 0,0,0);
          acc2[1][s] = __builtin_amdgcn_mfma_f32_16x16x32_f16(a1, b2cur[s], acc2[1][s], 0,0,0);
        }
#pragma unroll
        for (int s=0;s<2;++s) b2cur[s] = b2nxt[s];
      }
    }

    // ---- softmax over 4 z-gates, tanh candidate, combine (fp32 carry), store h fp32
    // z tile gt = 6+g*2+s : gt==6 -> accA[mt][6], else accB[mt][gt-7]
#pragma unroll
    for (int mt=0;mt<2;++mt)
#pragma unroll
      for (int s=0;s<2;++s){
        const int u = wave*32 + s*16 + l15;
        const float bz0 = bias[384 + u];
        const float bz1 = bias[512 + u];
        const float bz2 = bias[640 + u];
        const float bz3 = bias[768 + u];
        const float bij = bias[896 + u];
#pragma unroll
        for (int rg=0;rg<4;++rg){
          const int m = mt*16 + quad*4 + rg;
          const size_t row = (size_t)(bs+m)*UD + u;
          float z0 = ((s==0) ? accA[mt][6][rg] : accB[mt][0][rg]) + bz0;  // zi (gt=6+s)
          float z1 = accB[mt][1+s][rg] + bz1;                             // zl (gt=8+s)
          float z2 = accB[mt][3+s][rg] + bz2;                             // zt (gt=10+s)
          float z3 = accB[mt][5+s][rg] + bz3;                             // zd (gt=12+s)
          float mx = fmaxf(fmaxf(z0,z1), fmaxf(z2,z3));
          float e0 = __expf(z0-mx), e1 = __expf(z1-mx), e2 = __expf(z2-mx), e3 = __expf(z3-mx);
          float inv = 1.f/(e0+e1+e2+e3);
          float hl = hasL ? hLeft[row] : 0.f;
          float ht = hasT ? hTop[row]  : 0.f;
          float hd = hasD ? hDiag[row] : 0.f;
          float cand = tanhf(acc2[mt][s][rg] + bij);
          hOut[row] = (e1*hl + e2*ht + e3*hd + e0*cand)*inv;
        }
      }

    // ---- publish: all stores drained at barrier; release store = wbl2 (writeback
    // only, keeps clean WT lines resident) then sc1 flag store.
    __syncthreads();
    if (tid == 0)
      __hip_atomic_store(&flags[(size_t)cell*8 + strip], 1u,
                         __ATOMIC_RELEASE, __HIP_MEMORY_SCOPE_AGENT);
  }
}

extern "C" void kernel_launch(void* const* d_in, const int* in_sizes, int n_in,
                              void* d_out, int out_size, void* d_ws, size_t ws_size,
                              hipStream_t stream){
  const float* inp  = (const float*)d_in[0]; // (256,128,32,32) f32
  const float* W    = (const float*)d_in[1]; // (512,896) f32
  const float* Um   = (const float*)d_in[2]; // (384,128) f32
  const float* bias = (const float*)d_in[3]; // (1024,)  f32
  const float* wij  = (const float*)d_in[4]; // (128,128) f32
  float* out = (float*)d_out;                // (256,128) f32

  char* ws = (char*)d_ws;
  _Float16* WT    = (_Float16*)(ws);
  _Float16* B2T   = (_Float16*)(ws + WS_B2T);
  _Float16* X     = (_Float16*)(ws + WS_X);
  float*    H     = (float*)   (ws + WS_H);
  unsigned* flags = (unsigned*)(ws + WS_FLAG);

  k_reorder<<<dim3(256,32),256,0,stream>>>(inp, X);
  k_prep<<<1792,256,0,stream>>>(W, Um, wij, WT, B2T, flags);
  k_sweep<<<dim3(32,8),256,0,stream>>>(X, H, WT, B2T, bias, flags);
  k_out<<<128,256,0,stream>>>(H, out);
}

// Round 2
// 5626.301 us; speedup vs baseline: 1.0155x; 1.0155x over previous
//
#include <hip/hip_runtime.h>
#include <hip/hip_bf16.h>

typedef _Float16 f16x8 __attribute__((ext_vector_type(8)));
typedef float f32x4 __attribute__((ext_vector_type(4)));

#define BATCH 256
#define UD 128
#define K1 512
#define LDA 520    // 512 + 8 f16 pad
#define LDA2 392   // 384 + 8 f16 pad
#define CELLSZ (BATCH*UD)          // floats per grid cell

// Workspace layout (ws is 512 MiB):
//   WT    @ 0           : 896*512*2        =    917,504 B
//   B2T   @ 917,504     : 128*512*2        =    131,072 B
//   X     @ 1,048,576   : 1024*256*128*2   = 67,108,864 B
//   H     @ 68,157,440  : 1024*256*128*4   = 134,217,728 B  (write-once per cell)
//   flags @ 202,375,168 : 1024*8*4         =     32,768 B
#define WS_B2T  917504
#define WS_X    1048576
#define WS_H    68157440ull
#define WS_FLAG 202375168ull

// inputs (B,C,32,32) fp32 -> X[(i*32+j)][b][c] f16  (LDS transpose, coalesced both sides)
__global__ void k_reorder(const float* __restrict__ in, _Float16* __restrict__ X){
  int b = blockIdx.x, i = blockIdx.y;
  __shared__ float tile[128][33];
  int tid = threadIdx.x;
#pragma unroll
  for (int r=0;r<16;++r){
    int c = r*8 + (tid>>5), j = tid&31;
    tile[c][j] = in[(((size_t)b*128 + c)*32 + i)*32 + j];
  }
  __syncthreads();
#pragma unroll
  for (int r=0;r<16;++r){
    int j = r*2 + (tid>>7), c = tid&127;
    X[((size_t)(i*32 + j)*256 + b)*128 + c] = (_Float16)tile[c][j];
  }
}

// WT[n][k] = W[k][n]; B2T[n][k] = (k<384 ? Umat[k][n] : w_ij[k-384][n]); zero dep flags.
__global__ void k_prep(const float* __restrict__ W,
                       const float* __restrict__ Um,
                       const float* __restrict__ wij,
                       _Float16* __restrict__ WT, _Float16* __restrict__ B2T,
                       unsigned* __restrict__ flags){
  int idx = blockIdx.x*256 + threadIdx.x;
  if (idx < 896*512){
    int n = idx >> 9, k = idx & 511;
    WT[idx] = (_Float16)W[k*896 + n];
  }
  if (idx < 128*512){
    int n = idx >> 9, k = idx & 511;
    float v = (k < 384) ? Um[k*128 + n] : wij[(k-384)*128 + n];
    B2T[idx] = (_Float16)v;
  }
  if (idx < 1024*8) flags[idx] = 0;   // ws is poisoned each run -> must zero
}

// final h lives at cell (31,31) = 1023
__global__ void k_out(const float* __restrict__ H, float* __restrict__ out){
  int t = blockIdx.x*256 + threadIdx.x;
  out[t] = H[(size_t)1023*CELLSZ + t];
}

// GEMM1 pass over 7 of the 14 n-tiles (two-pass split keeps live VGPRs < 256 so
// __launch_bounds__(256,2) compiles spill-free; r-tiles die between passes).
// Tile map: tt 0..5 -> r cols wave*96 + tt*16 ; tt 6..13 -> z gate g=(tt-6)>>1, sub=(tt-6)&1.
template<int T0>
__device__ __forceinline__ void gemm1_pass(const _Float16* Al,
    const _Float16* __restrict__ WT, int wave, int l15, int quad,
    f32x4 (&acc)[2][7])
{
  const _Float16* bptr[7];
#pragma unroll
  for (int t=0;t<7;++t){
    const int tt = T0 + t;
    const int n = (tt<6) ? (wave*96 + tt*16)
                         : (384 + ((tt-6)>>1)*128 + wave*32 + ((tt-6)&1)*16);
    bptr[t] = WT + (size_t)(n + l15)*K1 + quad*8;
  }
  f16x8 bcur[7], bnxt[7];
#pragma unroll
  for (int t=0;t<7;++t) bcur[t] = *(const f16x8*)(bptr[t]);
#pragma unroll
  for (int ks=0; ks<16; ++ks){
    const int kb = ks*32 + quad*8;
    if (ks < 15){
#pragma unroll
      for (int t=0;t<7;++t) bnxt[t] = *(const f16x8*)(bptr[t] + (ks+1)*32);
    }
    f16x8 a0 = *(const f16x8*)&Al[l15*LDA + kb];
    f16x8 a1 = *(const f16x8*)&Al[(16+l15)*LDA + kb];
#pragma unroll
    for (int t=0;t<7;++t){
      acc[0][t] = __builtin_amdgcn_mfma_f32_16x16x32_f16(a0, bcur[t], acc[0][t], 0,0,0);
      acc[1][t] = __builtin_amdgcn_mfma_f32_16x16x32_f16(a1, bcur[t], acc[1][t], 0,0,0);
    }
#pragma unroll
    for (int t=0;t<7;++t) bcur[t] = bnxt[t];
  }
}

// R6: persistent wavefront kernel, NO release-wbl2 on the publish path.
// R5 post-mortem: __hip_atomic_store(RELEASE, AGENT) emits buffer_wbl2 (full L2
// dirty writeback) per cell publish -> 8192 L2 walks serialized per XCD, and all
// cross-track H reads forced to HBM (FETCH 4.27 GB, cell latency ~90 us).
// New scheme (XCD-mapping independent, Guideline 16 safe):
//   - each h element stored with RELAXED+AGENT atomic store (global_store sc1:
//     write-through to coherence point, no L2 dirty line, no wbl2 ever)
//   - publish = __syncthreads() (drains vmcnt for all waves) + RELAXED+AGENT flag
//   - consumer: RELAXED+AGENT poll -> __syncthreads -> PLAIN loads of H. Safe:
//     H is write-once and consumer caches first-touch an H line only after its
//     flag was observed (the step-d diag line was the step-(d-1) top line, also
//     read post-flag) -> stale copies cannot exist. WT/B2T stay clean+L2-resident.
__global__ __launch_bounds__(256, 2) void k_sweep(
    const _Float16* __restrict__ X,
    float* __restrict__ H,
    const _Float16* __restrict__ WT,
    const _Float16* __restrict__ B2T,
    const float* __restrict__ bias,
    unsigned* __restrict__ flags)
{
  __shared__ __align__(16) _Float16 Al[32*LDA];
  __shared__ __align__(16) _Float16 A2l[32*LDA2];

  const int c     = blockIdx.x;        // track index (32 tracks)
  const int strip = blockIdx.y;        // batch strip (8 x 32 rows)
  const int bs    = strip*32;

  const int tid  = threadIdx.x;
  const int wave = tid >> 6;
  const int lane = tid & 63;
  const int l15  = lane & 15;
  const int quad = lane >> 4;

  for (int d = c; d <= 62 - c; ++d){
    const int i0 = (d > 31) ? (d - 31) : 0;
    const int i  = i0 + c;
    const int j  = d - i;
    const bool hasT = (i >= 1);
    const bool hasL = (j >= 1);
    const bool hasD = hasT && hasL;

    const int cell = i*32 + j;
    const _Float16* Xc   = X + (size_t)cell*CELLSZ;
    float*       hOut    = H + (size_t)cell*CELLSZ;
    const float* hTop    = H + (size_t)(cell-32)*CELLSZ;  // valid iff hasT
    const float* hLeft   = H + (size_t)(cell-1)*CELLSZ;   // valid iff hasL
    const float* hDiag   = H + (size_t)(cell-33)*CELLSZ;  // valid iff hasD

    // ---- (A) stage s_ij + zero-fill absent h regions (no deps; overlaps the poll)
    for (int v = tid; v < 512; v += 256){
      int m = v >> 4, kc = (v & 15) << 3;
      *(uint4*)&Al[m*LDA + 384 + kc] = *(const uint4*)(Xc + (size_t)(bs+m)*UD + kc);
    }
    if (!hasT || !hasL){
#pragma unroll
      for (int r=0;r<3;++r){
        const bool present = (r==0) ? hasT : ((r==1) ? hasL : hasD);
        if (!present){
          for (int v = tid; v < 1024; v += 256){
            int m = v >> 5, kc = (v & 31) << 2;
            *(ushort4*)&Al[m*LDA + r*128 + kc] = make_ushort4(0,0,0,0);
          }
        }
      }
    }

    // ---- (B) wait for the 3 producer cells (same strip). Lanes 0..2 poll in lockstep.
    if (tid < 3){
      const unsigned* f = nullptr;
      if (tid==0 && hasT) f = &flags[(size_t)(cell-32)*8 + strip];
      if (tid==1 && hasL) f = &flags[(size_t)(cell-1)*8 + strip];
      if (tid==2 && hasD) f = &flags[(size_t)(cell-33)*8 + strip];
      if (f){
        while (__hip_atomic_load(f, __ATOMIC_RELAXED, __HIP_MEMORY_SCOPE_AGENT) == 0)
          __builtin_amdgcn_s_sleep(1);
      }
    }
    __syncthreads();

    // ---- (C) stage present neighbor h (fp32 -> f16), coalesced float4 (plain loads, see header)
    {
      const float* srcs[3];
      srcs[0] = hasT ? hTop : nullptr;
      srcs[1] = hasL ? hLeft : nullptr;
      srcs[2] = hasD ? hDiag : nullptr;
#pragma unroll
      for (int r=0;r<3;++r){
        const float* src = srcs[r];
        if (src){
          for (int v = tid; v < 1024; v += 256){
            int m = v >> 5, kc = (v & 31) << 2;
            float4 f4 = *(const float4*)(src + (size_t)(bs+m)*UD + kc);
            union { _Float16 h[4]; ushort4 u; } p;
            p.h[0]=(_Float16)f4.x; p.h[1]=(_Float16)f4.y;
            p.h[2]=(_Float16)f4.z; p.h[3]=(_Float16)f4.w;
            *(ushort4*)&Al[m*LDA + r*128 + kc] = p.u;
          }
        }
      }
    }
    __syncthreads();

    // ---- GEMM1 pass A: tiles 0..6 (all 6 r-tiles + z tile 6)
    f32x4 accA[2][7];
#pragma unroll
    for (int a=0;a<2;++a)
#pragma unroll
      for (int t=0;t<7;++t) accA[a][t] = (f32x4){0.f,0.f,0.f,0.f};
    gemm1_pass<0>(Al, WT, wave, l15, quad, accA);

    // ---- r = hard_sigmoid(.); A2 = r * h (re-ordered) -> LDS. r-tiles die here.
#pragma unroll
    for (int mt=0;mt<2;++mt)
#pragma unroll
      for (int t=0;t<6;++t){
        const int col = wave*96 + t*16 + l15;
        const float br = bias[col];
        const int hcol = (col < 128) ? (128 + col) : ((col < 256) ? (col - 128) : col);
#pragma unroll
        for (int rg=0;rg<4;++rg){
          const int m = mt*16 + quad*4 + rg;
          float r = 0.2f*(accA[mt][t][rg] + br) + 0.5f;
          r = fminf(fmaxf(r, 0.f), 1.f);
          float h = (float)Al[m*LDA + hcol];
          A2l[m*LDA2 + col] = (_Float16)(r*h);
        }
      }

    // ---- GEMM1 pass B: tiles 7..13 (remaining z-tiles)
    f32x4 accB[2][7];
#pragma unroll
    for (int a=0;a<2;++a)
#pragma unroll
      for (int t=0;t<7;++t) accB[a][t] = (f32x4){0.f,0.f,0.f,0.f};
    gemm1_pass<7>(Al, WT, wave, l15, quad, accB);
    __syncthreads();   // A2l writes (all waves) visible before GEMM2 reads

    // ---- GEMM2: (32 x 512) @ (512 x 128); k>=384 (s_ij) read from Al
    f32x4 acc2[2][2];
#pragma unroll
    for (int a=0;a<2;++a){ acc2[a][0]=(f32x4){0.f,0.f,0.f,0.f}; acc2[a][1]=(f32x4){0.f,0.f,0.f,0.f}; }
    {
      const _Float16* b2ptr[2];
#pragma unroll
      for (int s=0;s<2;++s) b2ptr[s] = B2T + (size_t)(wave*32 + s*16 + l15)*K1 + quad*8;
      f16x8 b2cur[2], b2nxt[2];
#pragma unroll
      for (int s=0;s<2;++s) b2cur[s] = *(const f16x8*)(b2ptr[s]);
#pragma unroll
      for (int ks=0; ks<16; ++ks){
        const int kb = ks*32 + quad*8;
        if (ks < 15){
#pragma unroll
          for (int s=0;s<2;++s) b2nxt[s] = *(const f16x8*)(b2ptr[s] + (ks+1)*32);
        }
        f16x8 a0, a1;
        if (ks < 12){
          a0 = *(const f16x8*)&A2l[l15*LDA2 + kb];
          a1 = *(const f16x8*)&A2l[(16+l15)*LDA2 + kb];
        } else {
          a0 = *(const f16x8*)&Al[l15*LDA + kb];
          a1 = *(const f16x8*)&Al[(16+l15)*LDA + kb];
        }
#pragma unroll
        for (int s=0;s<2;++s){
          acc2[0][s] = __builtin_amdgcn_mfma_f32_16x16x32_f16(a0, b2cur[s], acc2[0][s], 0,0,0);
          acc2[1][s] = __builtin_amdgcn_mfma_f32_16x16x32_f16(a1, b2cur[s], acc2[1][s], 0,0,0);
        }
#pragma unroll
        for (int s=0;s<2;++s) b2cur[s] = b2nxt[s];
      }
    }

    // ---- softmax over 4 z-gates, tanh candidate, combine (fp32 carry), store h
    // via RELAXED+AGENT atomic stores (sc1 write-through; no L2 dirty lines)
#pragma unroll
    for (int mt=0;mt<2;++mt)
#pragma unroll
      for (int s=0;s<2;++s){
        const int u = wave*32 + s*16 + l15;
        const float bz0 = bias[384 + u];
        const float bz1 = bias[512 + u];
        const float bz2 = bias[640 + u];
        const float bz3 = bias[768 + u];
        const float bij = bias[896 + u];
#pragma unroll
        for (int rg=0;rg<4;++rg){
          const int m = mt*16 + quad*4 + rg;
          const size_t row = (size_t)(bs+m)*UD + u;
          float z0 = ((s==0) ? accA[mt][6][rg] : accB[mt][0][rg]) + bz0;  // zi (gt=6+s)
          float z1 = accB[mt][1+s][rg] + bz1;                             // zl (gt=8+s)
          float z2 = accB[mt][3+s][rg] + bz2;                             // zt (gt=10+s)
          float z3 = accB[mt][5+s][rg] + bz3;                             // zd (gt=12+s)
          float mx = fmaxf(fmaxf(z0,z1), fmaxf(z2,z3));
          float e0 = __expf(z0-mx), e1 = __expf(z1-mx), e2 = __expf(z2-mx), e3 = __expf(z3-mx);
          float inv = 1.f/(e0+e1+e2+e3);
          float hl = hasL ? hLeft[row] : 0.f;
          float ht = hasT ? hTop[row]  : 0.f;
          float hd = hasD ? hDiag[row] : 0.f;
          float cand = tanhf(acc2[mt][s][rg] + bij);
          float hval = (e1*hl + e2*ht + e3*hd + e0*cand)*inv;
          __hip_atomic_store(&hOut[row], hval, __ATOMIC_RELAXED, __HIP_MEMORY_SCOPE_AGENT);
        }
      }

    // ---- publish: __syncthreads drains vmcnt(0) for ALL waves (sc1 stores acked
    // at coherence point), then a relaxed agent flag store. No wbl2 anywhere.
    __syncthreads();
    if (tid == 0)
      __hip_atomic_store(&flags[(size_t)cell*8 + strip], 1u,
                         __ATOMIC_RELAXED, __HIP_MEMORY_SCOPE_AGENT);
  }
}

extern "C" void kernel_launch(void* const* d_in, const int* in_sizes, int n_in,
                              void* d_out, int out_size, void* d_ws, size_t ws_size,
                              hipStream_t stream){
  const float* inp  = (const float*)d_in[0]; // (256,128,32,32) f32
  const float* W    = (const float*)d_in[1]; // (512,896) f32
  const float* Um   = (const float*)d_in[2]; // (384,128) f32
  const float* bias = (const float*)d_in[3]; // (1024,)  f32
  const float* wij  = (const float*)d_in[4]; // (128,128) f32
  float* out = (float*)d_out;                // (256,128) f32

  char* ws = (char*)d_ws;
  _Float16* WT    = (_Float16*)(ws);
  _Float16* B2T   = (_Float16*)(ws + WS_B2T);
  _Float16* X     = (_Float16*)(ws + WS_X);
  float*    H     = (float*)   (ws + WS_H);
  unsigned* flags = (unsigned*)(ws + WS_FLAG);

  k_reorder<<<dim3(256,32),256,0,stream>>>(inp, X);
  k_prep<<<1792,256,0,stream>>>(W, Um, wij, WT, B2T, flags);
  k_sweep<<<dim3(32,8),256,0,stream>>>(X, H, WT, B2T, bias, flags);
  k_out<<<128,256,0,stream>>>(H, out);
}

// Round 4
// 4438.932 us; speedup vs baseline: 1.2871x; 1.2675x over previous
//
#include <hip/hip_runtime.h>
#include <hip/hip_bf16.h>

typedef _Float16 f16x8 __attribute__((ext_vector_type(8)));
typedef float f32x4 __attribute__((ext_vector_type(4)));
typedef unsigned int u32x4 __attribute__((ext_vector_type(4)));  // clang vec: ok for nontemporal builtins

#define BATCH 256
#define UD 128
#define K1 512
#define LDA 520    // 512 + 8 f16 pad
#define LDA2 392   // 384 + 8 f16 pad
#define CELLSZ (BATCH*UD)          // floats per grid cell

// Workspace layout (ws is 512 MiB):
//   WT    @ 0           : 896*512*2        =    917,504 B
//   B2T   @ 917,504     : 128*512*2        =    131,072 B
//   X     @ 1,048,576   : 1024*256*128*2   = 67,108,864 B
//   H     @ 68,157,440  : 1024*256*128*4   = 134,217,728 B  (write-once per cell)
//   flags @ 202,375,168 : 1024*8*4         =     32,768 B
#define WS_B2T  917504
#define WS_X    1048576
#define WS_H    68157440ull
#define WS_FLAG 202375168ull

// inputs (B,C,32,32) fp32 -> X[(i*32+j)][b][c] f16  (LDS transpose, coalesced both sides)
__global__ void k_reorder(const float* __restrict__ in, _Float16* __restrict__ X){
  int b = blockIdx.x, i = blockIdx.y;
  __shared__ float tile[128][33];
  int tid = threadIdx.x;
#pragma unroll
  for (int r=0;r<16;++r){
    int c = r*8 + (tid>>5), j = tid&31;
    tile[c][j] = in[(((size_t)b*128 + c)*32 + i)*32 + j];
  }
  __syncthreads();
#pragma unroll
  for (int r=0;r<16;++r){
    int j = r*2 + (tid>>7), c = tid&127;
    X[((size_t)(i*32 + j)*256 + b)*128 + c] = (_Float16)tile[c][j];
  }
}

// WT[n][k] = W[k][n]; B2T[n][k] = (k<384 ? Umat[k][n] : w_ij[k-384][n]); zero dep flags.
__global__ void k_prep(const float* __restrict__ W,
                       const float* __restrict__ Um,
                       const float* __restrict__ wij,
                       _Float16* __restrict__ WT, _Float16* __restrict__ B2T,
                       unsigned* __restrict__ flags){
  int idx = blockIdx.x*256 + threadIdx.x;
  if (idx < 896*512){
    int n = idx >> 9, k = idx & 511;
    WT[idx] = (_Float16)W[k*896 + n];
  }
  if (idx < 128*512){
    int n = idx >> 9, k = idx & 511;
    float v = (k < 384) ? Um[k*128 + n] : wij[(k-384)*128 + n];
    B2T[idx] = (_Float16)v;
  }
  if (idx < 1024*8) flags[idx] = 0;   // ws is poisoned each run -> must zero
}

// final h lives at cell (31,31) = 1023
__global__ void k_out(const float* __restrict__ H, float* __restrict__ out){
  int t = blockIdx.x*256 + threadIdx.x;
  out[t] = H[(size_t)1023*CELLSZ + t];
}

// GEMM1 pass over 7 of the 14 n-tiles (two-pass split bounds live VGPRs;
// r-tiles die between passes).
// Tile map: tt 0..5 -> r cols wave*96 + tt*16 ; tt 6..13 -> z gate g=(tt-6)>>1, sub=(tt-6)&1.
template<int T0>
__device__ __forceinline__ void gemm1_pass(const _Float16* Al,
    const _Float16* __restrict__ WT, int wave, int l15, int quad,
    f32x4 (&acc)[2][7])
{
  const _Float16* bptr[7];
#pragma unroll
  for (int t=0;t<7;++t){
    const int tt = T0 + t;
    const int n = (tt<6) ? (wave*96 + tt*16)
                         : (384 + ((tt-6)>>1)*128 + wave*32 + ((tt-6)&1)*16);
    bptr[t] = WT + (size_t)(n + l15)*K1 + quad*8;
  }
  f16x8 bcur[7], bnxt[7];
#pragma unroll
  for (int t=0;t<7;++t) bcur[t] = *(const f16x8*)(bptr[t]);
#pragma unroll
  for (int ks=0; ks<16; ++ks){
    const int kb = ks*32 + quad*8;
    if (ks < 15){
#pragma unroll
      for (int t=0;t<7;++t) bnxt[t] = *(const f16x8*)(bptr[t] + (ks+1)*32);
    }
    f16x8 a0 = *(const f16x8*)&Al[l15*LDA + kb];
    f16x8 a1 = *(const f16x8*)&Al[(16+l15)*LDA + kb];
#pragma unroll
    for (int t=0;t<7;++t){
      acc[0][t] = __builtin_amdgcn_mfma_f32_16x16x32_f16(a0, bcur[t], acc[0][t], 0,0,0);
      acc[1][t] = __builtin_amdgcn_mfma_f32_16x16x32_f16(a1, bcur[t], acc[1][t], 0,0,0);
    }
#pragma unroll
    for (int t=0;t<7;++t) bcur[t] = bnxt[t];
  }
}

// R7b (R7 + nontemporal type fix): persistent wavefront, COLUMN tracks +
// coherent RMW flags.
// R6 post-mortem: relaxed-agent flag LOADS appear to be served from the stale
// local L2 (discovery latency = L2 eviction time ~tens of us = the whole cell
// time; MfmaUtil 2%, all pipes idle). Fix: poll AND publish flags with atomic
// RMW (__hip_atomic_fetch_add) which executes at the coherence point -> fresh
// value every poll, independent of cache state or XCD mapping.
// Column mapping: block (c,strip) owns column j=c, walks i=0..31.
//   left (i,c-1) = track c-1, 1 step earlier  -> poll its flag (covers diag too:
//   diag (i-1,c-1) was published by track c-1 before left, in program order)
//   top (i-1,c)  = OWN previous cell -> kept in 16 VGPRs (fp32) + f16 ds_write
//   into Al region0. One remote fetch fewer per cell; dep flow strictly c-1 -> c;
//   makespan = 63 balanced cells (row mapping's fold made it ~93).
// H data path unchanged from R6 (sc1 write-through stores; consumer plain loads
// are first-touch-after-flag so never stale).
__global__ __launch_bounds__(256, 1) void k_sweep(
    const _Float16* __restrict__ X,
    float* __restrict__ H,
    const _Float16* __restrict__ WT,
    const _Float16* __restrict__ B2T,
    const float* __restrict__ bias,
    unsigned* __restrict__ flags)
{
  __shared__ __align__(16) _Float16 Al[32*LDA];
  __shared__ __align__(16) _Float16 A2l[32*LDA2];

  const int c     = blockIdx.x;        // column / track index (32 tracks)
  const int strip = blockIdx.y;        // batch strip (8 x 32 rows)
  const int bs    = strip*32;

  const int tid  = threadIdx.x;
  const int wave = tid >> 6;
  const int lane = tid & 63;
  const int l15  = lane & 15;
  const int quad = lane >> 4;

  const bool hasL = (c >= 1);

  // ---- hoist biases into registers (invariant across the 32 cells)
  float br_reg[6];
#pragma unroll
  for (int t=0;t<6;++t) br_reg[t] = bias[wave*96 + t*16 + l15];
  float bz_reg[2][4], bij_reg[2];
#pragma unroll
  for (int s=0;s<2;++s){
    const int u = wave*32 + s*16 + l15;
#pragma unroll
    for (int g=0;g<4;++g) bz_reg[s][g] = bias[384 + g*128 + u];
    bij_reg[s] = bias[896 + u];
  }

  float hprev[2][2][4];   // own previous cell's h (fp32), [mt][s][rg]; valid for i>=1

  for (int i = 0; i < 32; ++i){
    const bool hasT = (i >= 1);
    const bool hasD = hasT && hasL;
    const int cell = i*32 + c;

    const _Float16* Xc   = X + (size_t)cell*CELLSZ;
    float*       hOut    = H + (size_t)cell*CELLSZ;
    const float* hLeft   = H + (size_t)(cell-1)*CELLSZ;   // valid iff hasL
    const float* hDiag   = H + (size_t)(cell-33)*CELLSZ;  // valid iff hasD

    // ---- (A) dep-free staging: X (nontemporal), own h_top f16 -> region0,
    //      zero-fill absent regions. Overlaps the poll.
    for (int v = tid; v < 512; v += 256){
      int m = v >> 4, kc = (v & 15) << 3;
      u32x4 xv = __builtin_nontemporal_load((const u32x4*)(Xc + (size_t)(bs+m)*UD + kc));
      *(u32x4*)&Al[m*LDA + 384 + kc] = xv;
    }
    if (hasT){
#pragma unroll
      for (int mt=0;mt<2;++mt)
#pragma unroll
        for (int s=0;s<2;++s)
#pragma unroll
          for (int rg=0;rg<4;++rg){
            const int m = mt*16 + quad*4 + rg;
            const int u = wave*32 + s*16 + l15;
            Al[m*LDA + u] = (_Float16)hprev[mt][s][rg];   // region0 = h_top
          }
    } else {
      for (int v = tid; v < 1024; v += 256){
        int m = v >> 5, kc = (v & 31) << 2;
        *(ushort4*)&Al[m*LDA + 0*128 + kc] = make_ushort4(0,0,0,0);
      }
    }
    if (!hasL){
      for (int v = tid; v < 1024; v += 256){
        int m = v >> 5, kc = (v & 31) << 2;
        *(ushort4*)&Al[m*LDA + 1*128 + kc] = make_ushort4(0,0,0,0);
      }
    }
    if (!hasD){
      for (int v = tid; v < 1024; v += 256){
        int m = v >> 5, kc = (v & 31) << 2;
        *(ushort4*)&Al[m*LDA + 2*128 + kc] = make_ushort4(0,0,0,0);
      }
    }

    // ---- (B) wait for left producer (track c-1). RMW poll = coherence-point read.
    if (hasL && tid == 0){
      unsigned* f = &flags[(size_t)(cell-1)*8 + strip];
      while (__hip_atomic_fetch_add(f, 0u, __ATOMIC_RELAXED, __HIP_MEMORY_SCOPE_AGENT) == 0)
        __builtin_amdgcn_s_sleep(4);
    }
    __syncthreads();

    // ---- (C) stage h_left (region1) and h_diag (region2), fp32 -> f16, plain loads
    if (hasL){
      for (int v = tid; v < 1024; v += 256){
        int m = v >> 5, kc = (v & 31) << 2;
        float4 f4 = *(const float4*)(hLeft + (size_t)(bs+m)*UD + kc);
        union { _Float16 h[4]; ushort4 u; } p;
        p.h[0]=(_Float16)f4.x; p.h[1]=(_Float16)f4.y;
        p.h[2]=(_Float16)f4.z; p.h[3]=(_Float16)f4.w;
        *(ushort4*)&Al[m*LDA + 1*128 + kc] = p.u;
      }
    }
    if (hasD){
      for (int v = tid; v < 1024; v += 256){
        int m = v >> 5, kc = (v & 31) << 2;
        float4 f4 = *(const float4*)(hDiag + (size_t)(bs+m)*UD + kc);
        union { _Float16 h[4]; ushort4 u; } p;
        p.h[0]=(_Float16)f4.x; p.h[1]=(_Float16)f4.y;
        p.h[2]=(_Float16)f4.z; p.h[3]=(_Float16)f4.w;
        *(ushort4*)&Al[m*LDA + 2*128 + kc] = p.u;
      }
    }
    __syncthreads();

    // ---- GEMM1 pass A: tiles 0..6 (all 6 r-tiles + z tile 6)
    f32x4 accA[2][7];
#pragma unroll
    for (int a=0;a<2;++a)
#pragma unroll
      for (int t=0;t<7;++t) accA[a][t] = (f32x4){0.f,0.f,0.f,0.f};
    gemm1_pass<0>(Al, WT, wave, l15, quad, accA);

    // ---- r = hard_sigmoid(.); A2 = r * h (re-ordered) -> LDS. r-tiles die here.
#pragma unroll
    for (int mt=0;mt<2;++mt)
#pragma unroll
      for (int t=0;t<6;++t){
        const int col = wave*96 + t*16 + l15;
        const float br = br_reg[t];
        const int hcol = (col < 128) ? (128 + col) : ((col < 256) ? (col - 128) : col);
#pragma unroll
        for (int rg=0;rg<4;++rg){
          const int m = mt*16 + quad*4 + rg;
          float r = 0.2f*(accA[mt][t][rg] + br) + 0.5f;
          r = fminf(fmaxf(r, 0.f), 1.f);
          float h = (float)Al[m*LDA + hcol];
          A2l[m*LDA2 + col] = (_Float16)(r*h);
        }
      }

    // ---- GEMM1 pass B: tiles 7..13 (remaining z-tiles)
    f32x4 accB[2][7];
#pragma unroll
    for (int a=0;a<2;++a)
#pragma unroll
      for (int t=0;t<7;++t) accB[a][t] = (f32x4){0.f,0.f,0.f,0.f};
    gemm1_pass<7>(Al, WT, wave, l15, quad, accB);
    __syncthreads();   // A2l writes (all waves) visible before GEMM2 reads

    // ---- GEMM2: (32 x 512) @ (512 x 128); k>=384 (s_ij) read from Al
    f32x4 acc2[2][2];
#pragma unroll
    for (int a=0;a<2;++a){ acc2[a][0]=(f32x4){0.f,0.f,0.f,0.f}; acc2[a][1]=(f32x4){0.f,0.f,0.f,0.f}; }
    {
      const _Float16* b2ptr[2];
#pragma unroll
      for (int s=0;s<2;++s) b2ptr[s] = B2T + (size_t)(wave*32 + s*16 + l15)*K1 + quad*8;
      f16x8 b2cur[2], b2nxt[2];
#pragma unroll
      for (int s=0;s<2;++s) b2cur[s] = *(const f16x8*)(b2ptr[s]);
#pragma unroll
      for (int ks=0; ks<16; ++ks){
        const int kb = ks*32 + quad*8;
        if (ks < 15){
#pragma unroll
          for (int s=0;s<2;++s) b2nxt[s] = *(const f16x8*)(b2ptr[s] + (ks+1)*32);
        }
        f16x8 a0, a1;
        if (ks < 12){
          a0 = *(const f16x8*)&A2l[l15*LDA2 + kb];
          a1 = *(const f16x8*)&A2l[(16+l15)*LDA2 + kb];
        } else {
          a0 = *(const f16x8*)&Al[l15*LDA + kb];
          a1 = *(const f16x8*)&Al[(16+l15)*LDA + kb];
        }
#pragma unroll
        for (int s=0;s<2;++s){
          acc2[0][s] = __builtin_amdgcn_mfma_f32_16x16x32_f16(a0, b2cur[s], acc2[0][s], 0,0,0);
          acc2[1][s] = __builtin_amdgcn_mfma_f32_16x16x32_f16(a1, b2cur[s], acc2[1][s], 0,0,0);
        }
#pragma unroll
        for (int s=0;s<2;++s) b2cur[s] = b2nxt[s];
      }
    }

    // ---- softmax over 4 z-gates, tanh candidate, combine (fp32 carry)
    // ht from hprev regs; hl/hd re-read (stage-C-cached lines). h stored via
    // RELAXED+AGENT sc1 write-through (coherence-point visible, no wbl2).
#pragma unroll
    for (int mt=0;mt<2;++mt)
#pragma unroll
      for (int s=0;s<2;++s){
#pragma unroll
        for (int rg=0;rg<4;++rg){
          const int m = mt*16 + quad*4 + rg;
          const int u = wave*32 + s*16 + l15;
          const size_t row = (size_t)(bs+m)*UD + u;
          float z0 = ((s==0) ? accA[mt][6][rg] : accB[mt][0][rg]) + bz_reg[s][0];  // zi
          float z1 = accB[mt][1+s][rg] + bz_reg[s][1];                             // zl
          float z2 = accB[mt][3+s][rg] + bz_reg[s][2];                             // zt
          float z3 = accB[mt][5+s][rg] + bz_reg[s][3];                             // zd
          float mx = fmaxf(fmaxf(z0,z1), fmaxf(z2,z3));
          float e0 = __expf(z0-mx), e1 = __expf(z1-mx), e2 = __expf(z2-mx), e3 = __expf(z3-mx);
          float inv = 1.f/(e0+e1+e2+e3);
          float hl = hasL ? hLeft[row] : 0.f;
          float ht = hasT ? hprev[mt][s][rg] : 0.f;
          float hd = hasD ? hDiag[row] : 0.f;
          float cand = tanhf(acc2[mt][s][rg] + bij_reg[s]);
          float hval = (e1*hl + e2*ht + e3*hd + e0*cand)*inv;
          __hip_atomic_store(&hOut[row], hval, __ATOMIC_RELAXED, __HIP_MEMORY_SCOPE_AGENT);
          hprev[mt][s][rg] = hval;
        }
      }

    // ---- publish: barrier drains vmcnt (sc1 stores acked at coherence point),
    // then flag via RMW (coherence-point write, fresh for any consumer RMW poll).
    __syncthreads();
    if (tid == 0)
      __hip_atomic_fetch_add(&flags[(size_t)cell*8 + strip], 1u,
                             __ATOMIC_RELAXED, __HIP_MEMORY_SCOPE_AGENT);
  }
}

extern "C" void kernel_launch(void* const* d_in, const int* in_sizes, int n_in,
                              void* d_out, int out_size, void* d_ws, size_t ws_size,
                              hipStream_t stream){
  const float* inp  = (const float*)d_in[0]; // (256,128,32,32) f32
  const float* W    = (const float*)d_in[1]; // (512,896) f32
  const float* Um   = (const float*)d_in[2]; // (384,128) f32
  const float* bias = (const float*)d_in[3]; // (1024,)  f32
  const float* wij  = (const float*)d_in[4]; // (128,128) f32
  float* out = (float*)d_out;                // (256,128) f32

  char* ws = (char*)d_ws;
  _Float16* WT    = (_Float16*)(ws);
  _Float16* B2T   = (_Float16*)(ws + WS_B2T);
  _Float16* X     = (_Float16*)(ws + WS_X);
  float*    H     = (float*)   (ws + WS_H);
  unsigned* flags = (unsigned*)(ws + WS_FLAG);

  k_reorder<<<dim3(256,32),256,0,stream>>>(inp, X);
  k_prep<<<1792,256,0,stream>>>(W, Um, wij, WT, B2T, flags);
  k_sweep<<<dim3(32,8),256,0,stream>>>(X, H, WT, B2T, bias, flags);
  k_out<<<128,256,0,stream>>>(H, out);
}

// Round 5
// 4327.277 us; speedup vs baseline: 1.3203x; 1.0258x over previous
//
#include <hip/hip_runtime.h>
#include <hip/hip_bf16.h>

typedef _Float16 f16x8 __attribute__((ext_vector_type(8)));
typedef float f32x4 __attribute__((ext_vector_type(4)));
typedef unsigned int u32x4 __attribute__((ext_vector_type(4)));  // clang vec for nontemporal builtins

#define BATCH 256
#define UD 128
#define K1 512
#define LDA 520    // 512 + 8 f16 pad
#define LDA2 392   // 384 + 8 f16 pad
#define CELLSZ (BATCH*UD)          // floats per grid cell

// Workspace layout (ws is 512 MiB):
//   WT    @ 0           : 896*512*2        =    917,504 B
//   B2T   @ 917,504     : 128*512*2        =    131,072 B
//   X     @ 1,048,576   : 1024*256*128*2   = 67,108,864 B
//   H     @ 68,157,440  : 1024*256*128*4   = 134,217,728 B  (write-once per cell)
//   flags @ 202,375,168 : 1024*8*4         =     32,768 B
#define WS_B2T  917504
#define WS_X    1048576
#define WS_H    68157440ull
#define WS_FLAG 202375168ull

// inputs (B,C,32,32) fp32 -> X[(i*32+j)][b][c] f16  (LDS transpose, coalesced both sides)
__global__ void k_reorder(const float* __restrict__ in, _Float16* __restrict__ X){
  int b = blockIdx.x, i = blockIdx.y;
  __shared__ float tile[128][33];
  int tid = threadIdx.x;
#pragma unroll
  for (int r=0;r<16;++r){
    int c = r*8 + (tid>>5), j = tid&31;
    tile[c][j] = in[(((size_t)b*128 + c)*32 + i)*32 + j];
  }
  __syncthreads();
#pragma unroll
  for (int r=0;r<16;++r){
    int j = r*2 + (tid>>7), c = tid&127;
    X[((size_t)(i*32 + j)*256 + b)*128 + c] = (_Float16)tile[c][j];
  }
}

// WT[n][k] = W[k][n]; B2T[n][k] = (k<384 ? Umat[k][n] : w_ij[k-384][n]); zero dep flags.
// Flags zeroed via AGENT atomic store (coherence-point write) — a plain store could
// sit dirty in one XCD L2 and later clobber a producer's published flag.
__global__ void k_prep(const float* __restrict__ W,
                       const float* __restrict__ Um,
                       const float* __restrict__ wij,
                       _Float16* __restrict__ WT, _Float16* __restrict__ B2T,
                       unsigned* __restrict__ flags){
  int idx = blockIdx.x*256 + threadIdx.x;
  if (idx < 896*512){
    int n = idx >> 9, k = idx & 511;
    WT[idx] = (_Float16)W[k*896 + n];
  }
  if (idx < 128*512){
    int n = idx >> 9, k = idx & 511;
    float v = (k < 384) ? Um[k*128 + n] : wij[(k-384)*128 + n];
    B2T[idx] = (_Float16)v;
  }
  if (idx < 1024*8)
    __hip_atomic_store(&flags[idx], 0u, __ATOMIC_RELAXED, __HIP_MEMORY_SCOPE_AGENT);
}

// final h lives at cell (31,31) = 1023
__global__ void k_out(const float* __restrict__ H, float* __restrict__ out){
  int t = blockIdx.x*256 + threadIdx.x;
  out[t] = H[(size_t)1023*CELLSZ + t];
}

// GEMM1 pass over 7 of the 14 n-tiles, DEPTH-2 B prefetch (R8: iter period was
// gated by 1-deep prefetch x full load latency with 1 wave/SIMD and no overlap).
// Tile map: tt 0..5 -> r cols wave*96 + tt*16 ; tt 6..13 -> z gate g=(tt-6)>>1, sub=(tt-6)&1.
template<int T0>
__device__ __forceinline__ void gemm1_pass(const _Float16* Al,
    const _Float16* __restrict__ WT, int wave, int l15, int quad,
    f32x4 (&acc)[2][7])
{
  const _Float16* bptr[7];
#pragma unroll
  for (int t=0;t<7;++t){
    const int tt = T0 + t;
    const int n = (tt<6) ? (wave*96 + tt*16)
                         : (384 + ((tt-6)>>1)*128 + wave*32 + ((tt-6)&1)*16);
    bptr[t] = WT + (size_t)(n + l15)*K1 + quad*8;
  }
  f16x8 ba[7], bb[7];
#pragma unroll
  for (int t=0;t<7;++t) ba[t] = *(const f16x8*)(bptr[t]);
#pragma unroll
  for (int t=0;t<7;++t) bb[t] = *(const f16x8*)(bptr[t] + 32);
#pragma unroll
  for (int ks=0; ks<16; ++ks){
    const int kb = ks*32 + quad*8;
    f16x8 bn[7];
    if (ks < 14){
#pragma unroll
      for (int t=0;t<7;++t) bn[t] = *(const f16x8*)(bptr[t] + (ks+2)*32);
    }
    f16x8 a0 = *(const f16x8*)&Al[l15*LDA + kb];
    f16x8 a1 = *(const f16x8*)&Al[(16+l15)*LDA + kb];
#pragma unroll
    for (int t=0;t<7;++t){
      acc[0][t] = __builtin_amdgcn_mfma_f32_16x16x32_f16(a0, ba[t], acc[0][t], 0,0,0);
      acc[1][t] = __builtin_amdgcn_mfma_f32_16x16x32_f16(a1, ba[t], acc[1][t], 0,0,0);
    }
#pragma unroll
    for (int t=0;t<7;++t) ba[t] = bb[t];
    if (ks < 14){
#pragma unroll
      for (int t=0;t<7;++t) bb[t] = bn[t];
    }
  }
}

// R8: persistent column-track wavefront (R7b structure) + L2-residency fixes.
// R7b post-mortem: per-hop latency ~66us unchanged by flag mechanism; the cell
// itself is latency-bound: 1 wave/SIMD, 1-deep B prefetch, and B-streams MISS L2
// because X/H streaming (~2.5MB/XCD/cell) churns the 4MB L2 and evicts WT
// (FETCH 3.1MB/cell ~ WT-sized re-miss every cell).
// Fixes: (1) nontemporal on all streaming reads (X, hLeft) so WT+B2T (~1MB)
// stay L2-resident -> B-loads become L2 hits; (2) hDiag global fetch ELIMINATED:
// hDiag(step i) = hLeft(step i-1), kept in an LDS fp32 double buffer; epilogue
// hl/hd read from LDS (bit-identical fp32); (3) depth-2 B prefetch halves
// exposed latency per K-iter.
__global__ __launch_bounds__(256, 1) void k_sweep(
    const _Float16* __restrict__ X,
    float* __restrict__ H,
    const _Float16* __restrict__ WT,
    const _Float16* __restrict__ B2T,
    const float* __restrict__ bias,
    unsigned* __restrict__ flags)
{
  __shared__ __align__(16) _Float16 Al[32*LDA];
  __shared__ __align__(16) _Float16 A2l[32*LDA2];
  __shared__ __align__(16) float HLbuf[2][32*UD];   // fp32 hLeft history: [i&1]=cur, [^1]=prev(=hDiag)

  const int c     = blockIdx.x;        // column / track index (32 tracks)
  const int strip = blockIdx.y;        // batch strip (8 x 32 rows)
  const int bs    = strip*32;

  const int tid  = threadIdx.x;
  const int wave = tid >> 6;
  const int lane = tid & 63;
  const int l15  = lane & 15;
  const int quad = lane >> 4;

  const bool hasL = (c >= 1);

  // ---- hoist biases into registers (invariant across the 32 cells)
  float br_reg[6];
#pragma unroll
  for (int t=0;t<6;++t) br_reg[t] = bias[wave*96 + t*16 + l15];
  float bz_reg[2][4], bij_reg[2];
#pragma unroll
  for (int s=0;s<2;++s){
    const int u = wave*32 + s*16 + l15;
#pragma unroll
    for (int g=0;g<4;++g) bz_reg[s][g] = bias[384 + g*128 + u];
    bij_reg[s] = bias[896 + u];
  }

  float hprev[2][2][4];   // own previous cell's h (fp32), [mt][s][rg]; valid for i>=1

  for (int i = 0; i < 32; ++i){
    const bool hasT = (i >= 1);
    const bool hasD = hasT && hasL;
    const int cell = i*32 + c;

    const _Float16* Xc   = X + (size_t)cell*CELLSZ;
    float*       hOut    = H + (size_t)cell*CELLSZ;
    const float* hLeft   = H + (size_t)(cell-1)*CELLSZ;   // valid iff hasL
    float*       HLcur   = HLbuf[i & 1];
    const float* HLprev  = HLbuf[(i & 1) ^ 1];            // staged last step = hDiag fp32

    // ---- (A) dep-free staging: X (nontemporal), own h_top f16 -> region0,
    //      zero-fill absent regions. Overlaps the poll.
    for (int v = tid; v < 512; v += 256){
      int m = v >> 4, kc = (v & 15) << 3;
      u32x4 xv = __builtin_nontemporal_load((const u32x4*)(Xc + (size_t)(bs+m)*UD + kc));
      *(u32x4*)&Al[m*LDA + 384 + kc] = xv;
    }
    if (hasT){
#pragma unroll
      for (int mt=0;mt<2;++mt)
#pragma unroll
        for (int s=0;s<2;++s)
#pragma unroll
          for (int rg=0;rg<4;++rg){
            const int m = mt*16 + quad*4 + rg;
            const int u = wave*32 + s*16 + l15;
            Al[m*LDA + u] = (_Float16)hprev[mt][s][rg];   // region0 = h_top
          }
    } else {
      for (int v = tid; v < 1024; v += 256){
        int m = v >> 5, kc = (v & 31) << 2;
        *(ushort4*)&Al[m*LDA + 0*128 + kc] = make_ushort4(0,0,0,0);
      }
    }
    if (!hasL){
      for (int v = tid; v < 1024; v += 256){
        int m = v >> 5, kc = (v & 31) << 2;
        *(ushort4*)&Al[m*LDA + 1*128 + kc] = make_ushort4(0,0,0,0);
      }
    }
    if (!hasD){
      for (int v = tid; v < 1024; v += 256){
        int m = v >> 5, kc = (v & 31) << 2;
        *(ushort4*)&Al[m*LDA + 2*128 + kc] = make_ushort4(0,0,0,0);
      }
    }

    // ---- (B) wait for left producer (track c-1). RMW poll = coherence-point read.
    if (hasL && tid == 0){
      unsigned* f = &flags[(size_t)(cell-1)*8 + strip];
      while (__hip_atomic_fetch_add(f, 0u, __ATOMIC_RELAXED, __HIP_MEMORY_SCOPE_AGENT) == 0)
        __builtin_amdgcn_s_sleep(2);
    }
    __syncthreads();

    // ---- (C) stage hLeft (nontemporal, ONLY remote read): f16 -> region1 and
    //      fp32 -> HLcur. Region2 (hDiag) built from HLprev (LDS, staged last step).
    if (hasL){
      for (int v = tid; v < 1024; v += 256){
        int m = v >> 5, kc = (v & 31) << 2;
        f32x4 f4 = __builtin_nontemporal_load((const f32x4*)(hLeft + (size_t)(bs+m)*UD + kc));
        union { _Float16 h[4]; ushort4 u; } p;
        p.h[0]=(_Float16)f4.x; p.h[1]=(_Float16)f4.y;
        p.h[2]=(_Float16)f4.z; p.h[3]=(_Float16)f4.w;
        *(ushort4*)&Al[m*LDA + 1*128 + kc] = p.u;
        *(f32x4*)&HLcur[m*UD + kc] = f4;
      }
    }
    if (hasD){
      for (int v = tid; v < 1024; v += 256){
        int m = v >> 5, kc = (v & 31) << 2;
        f32x4 f4 = *(const f32x4*)&HLprev[m*UD + kc];
        union { _Float16 h[4]; ushort4 u; } p;
        p.h[0]=(_Float16)f4.x; p.h[1]=(_Float16)f4.y;
        p.h[2]=(_Float16)f4.z; p.h[3]=(_Float16)f4.w;
        *(ushort4*)&Al[m*LDA + 2*128 + kc] = p.u;
      }
    }
    __syncthreads();

    // ---- GEMM1 pass A: tiles 0..6 (all 6 r-tiles + z tile 6)
    f32x4 accA[2][7];
#pragma unroll
    for (int a=0;a<2;++a)
#pragma unroll
      for (int t=0;t<7;++t) accA[a][t] = (f32x4){0.f,0.f,0.f,0.f};
    gemm1_pass<0>(Al, WT, wave, l15, quad, accA);

    // ---- r = hard_sigmoid(.); A2 = r * h (re-ordered) -> LDS. r-tiles die here.
#pragma unroll
    for (int mt=0;mt<2;++mt)
#pragma unroll
      for (int t=0;t<6;++t){
        const int col = wave*96 + t*16 + l15;
        const float br = br_reg[t];
        const int hcol = (col < 128) ? (128 + col) : ((col < 256) ? (col - 128) : col);
#pragma unroll
        for (int rg=0;rg<4;++rg){
          const int m = mt*16 + quad*4 + rg;
          float r = 0.2f*(accA[mt][t][rg] + br) + 0.5f;
          r = fminf(fmaxf(r, 0.f), 1.f);
          float h = (float)Al[m*LDA + hcol];
          A2l[m*LDA2 + col] = (_Float16)(r*h);
        }
      }

    // ---- GEMM1 pass B: tiles 7..13 (remaining z-tiles)
    f32x4 accB[2][7];
#pragma unroll
    for (int a=0;a<2;++a)
#pragma unroll
      for (int t=0;t<7;++t) accB[a][t] = (f32x4){0.f,0.f,0.f,0.f};
    gemm1_pass<7>(Al, WT, wave, l15, quad, accB);
    __syncthreads();   // A2l writes (all waves) visible before GEMM2 reads

    // ---- GEMM2: (32 x 512) @ (512 x 128); k>=384 (s_ij) read from Al. Depth-2 B prefetch.
    f32x4 acc2[2][2];
#pragma unroll
    for (int a=0;a<2;++a){ acc2[a][0]=(f32x4){0.f,0.f,0.f,0.f}; acc2[a][1]=(f32x4){0.f,0.f,0.f,0.f}; }
    {
      const _Float16* b2ptr[2];
#pragma unroll
      for (int s=0;s<2;++s) b2ptr[s] = B2T + (size_t)(wave*32 + s*16 + l15)*K1 + quad*8;
      f16x8 ba[2], bb[2];
#pragma unroll
      for (int s=0;s<2;++s) ba[s] = *(const f16x8*)(b2ptr[s]);
#pragma unroll
      for (int s=0;s<2;++s) bb[s] = *(const f16x8*)(b2ptr[s] + 32);
#pragma unroll
      for (int ks=0; ks<16; ++ks){
        const int kb = ks*32 + quad*8;
        f16x8 bn[2];
        if (ks < 14){
#pragma unroll
          for (int s=0;s<2;++s) bn[s] = *(const f16x8*)(b2ptr[s] + (ks+2)*32);
        }
        f16x8 a0, a1;
        if (ks < 12){
          a0 = *(const f16x8*)&A2l[l15*LDA2 + kb];
          a1 = *(const f16x8*)&A2l[(16+l15)*LDA2 + kb];
        } else {
          a0 = *(const f16x8*)&Al[l15*LDA + kb];
          a1 = *(const f16x8*)&Al[(16+l15)*LDA + kb];
        }
#pragma unroll
        for (int s=0;s<2;++s){
          acc2[0][s] = __builtin_amdgcn_mfma_f32_16x16x32_f16(a0, ba[s], acc2[0][s], 0,0,0);
          acc2[1][s] = __builtin_amdgcn_mfma_f32_16x16x32_f16(a1, ba[s], acc2[1][s], 0,0,0);
        }
#pragma unroll
        for (int s=0;s<2;++s) ba[s] = bb[s];
        if (ks < 14){
#pragma unroll
          for (int s=0;s<2;++s) bb[s] = bn[s];
        }
      }
    }

    // ---- softmax over 4 z-gates, tanh candidate, combine (fp32 carry)
    // ht from hprev regs; hl/hd from LDS fp32 buffers (bit-identical to global).
    // h stored via RELAXED+AGENT sc1 write-through (coherence-point visible).
#pragma unroll
    for (int mt=0;mt<2;++mt)
#pragma unroll
      for (int s=0;s<2;++s){
#pragma unroll
        for (int rg=0;rg<4;++rg){
          const int m = mt*16 + quad*4 + rg;
          const int u = wave*32 + s*16 + l15;
          const size_t row = (size_t)(bs+m)*UD + u;
          float z0 = ((s==0) ? accA[mt][6][rg] : accB[mt][0][rg]) + bz_reg[s][0];  // zi
          float z1 = accB[mt][1+s][rg] + bz_reg[s][1];                             // zl
          float z2 = accB[mt][3+s][rg] + bz_reg[s][2];                             // zt
          float z3 = accB[mt][5+s][rg] + bz_reg[s][3];                             // zd
          float mx = fmaxf(fmaxf(z0,z1), fmaxf(z2,z3));
          float e0 = __expf(z0-mx), e1 = __expf(z1-mx), e2 = __expf(z2-mx), e3 = __expf(z3-mx);
          float inv = 1.f/(e0+e1+e2+e3);
          float hl = hasL ? HLcur[m*UD + u] : 0.f;
          float ht = hasT ? hprev[mt][s][rg] : 0.f;
          float hd = hasD ? HLprev[m*UD + u] : 0.f;
          float cand = tanhf(acc2[mt][s][rg] + bij_reg[s]);
          float hval = (e1*hl + e2*ht + e3*hd + e0*cand)*inv;
          __hip_atomic_store(&hOut[row], hval, __ATOMIC_RELAXED, __HIP_MEMORY_SCOPE_AGENT);
          hprev[mt][s][rg] = hval;
        }
      }

    // ---- publish: barrier drains vmcnt (sc1 stores acked at coherence point),
    // then flag via RMW (coherence-point write, fresh for any consumer RMW poll).
    __syncthreads();
    if (tid == 0)
      __hip_atomic_fetch_add(&flags[(size_t)cell*8 + strip], 1u,
                             __ATOMIC_RELAXED, __HIP_MEMORY_SCOPE_AGENT);
  }
}

extern "C" void kernel_launch(void* const* d_in, const int* in_sizes, int n_in,
                              void* d_out, int out_size, void* d_ws, size_t ws_size,
                              hipStream_t stream){
  const float* inp  = (const float*)d_in[0]; // (256,128,32,32) f32
  const float* W    = (const float*)d_in[1]; // (512,896) f32
  const float* Um   = (const float*)d_in[2]; // (384,128) f32
  const float* bias = (const float*)d_in[3]; // (1024,)  f32
  const float* wij  = (const float*)d_in[4]; // (128,128) f32
  float* out = (float*)d_out;                // (256,128) f32

  char* ws = (char*)d_ws;
  _Float16* WT    = (_Float16*)(ws);
  _Float16* B2T   = (_Float16*)(ws + WS_B2T);
  _Float16* X     = (_Float16*)(ws + WS_X);
  float*    H     = (float*)   (ws + WS_H);
  unsigned* flags = (unsigned*)(ws + WS_FLAG);

  k_reorder<<<dim3(256,32),256,0,stream>>>(inp, X);
  k_prep<<<1792,256,0,stream>>>(W, Um, wij, WT, B2T, flags);
  k_sweep<<<dim3(32,8),256,0,stream>>>(X, H, WT, B2T, bias, flags);
  k_out<<<128,256,0,stream>>>(H, out);
}